// Round 14
// baseline (661.352 us; speedup 1.0000x reference)
//
#include <hip/hip_runtime.h>
#include <hip/hip_bf16.h>
#include <cstdint>
#include <cstddef>

#define B_    16
#define SEQ_  512
#define CIN_  321
#define PRED_ 96
#define DM_   512
#define DI_   1024
#define NST_  16
#define RNK_  32
#define L_    321
#define NT_   (B_*CIN_)   // 5136 tokens
#define PADM_ 5248        // NT_ padded to multiple of 128 for OOB-safe tile reads
#define TC_   41          // scan chunk length (8 chunks: 7x41 + 34)
#define NC_   8
#define PS_   384         // padded CIN for stats partials

typedef unsigned short ushort_t;
typedef __bf16 bf16x8 __attribute__((ext_vector_type(8)));
typedef float  f32x4  __attribute__((ext_vector_type(4)));
typedef __attribute__((address_space(3))) void lds_void_t;
typedef const __attribute__((address_space(1))) void gbl_void_t;

__device__ __forceinline__ float sigmoidf_(float x){ return 1.f/(1.f+__expf(-x)); }
__device__ __forceinline__ float softplusf_(float x){
    return (x > 15.f) ? x : __logf(1.f + __expf(x));
}
__device__ __forceinline__ ushort_t f2bf(float f){
    union { float f; unsigned u; } v; v.f = f;
    unsigned r = v.u + 0x7FFF + ((v.u >> 16) & 1);
    return (ushort_t)(r >> 16);
}
__device__ __forceinline__ float bf2f(ushort_t u){
    return __uint_as_float(((unsigned)u) << 16);
}
__device__ __forceinline__ f32x4 bf4_to_f4(ushort4 u){
    f32x4 r; r[0]=bf2f(u.x); r[1]=bf2f(u.y); r[2]=bf2f(u.z); r[3]=bf2f(u.w);
    return r;
}

// ============================ epilogues (z-batched: epi(z,m,n,v)) ============================
struct EpiBiasDual {          // embed: fp32 residual + bf16 copy
    float* C; ushort_t* Cb; const float* bias;
    __device__ void operator()(int z, int m, int n, float v) const {
        float o = v + bias[n];
        C[(size_t)m*DM_ + n] = o;
        Cb[(size_t)m*DM_ + n] = f2bf(o);
    }
};
struct EpiXZ2 {               // merged-dir in_proj: N=4096, dir = n>>11; z=1 rows flipped
    ushort_t* xzb;
    __device__ void operator()(int, int m, int n, float v) const {
        int z = n >> 11, nn = n & 2047;
        int mm = m;
        if (z) { int b = m / L_; int l = m - b*L_; mm = b*L_ + (L_-1 - l); }
        xzb[(size_t)z*PADM_*2*DI_ + (size_t)mm*(2*DI_) + nn] = f2bf(v);
    }
};
struct EpiDbl {               // x_proj: dt (n<32) -> bf16 dtb; B/C (32<=n<64) -> bf16 dbcb
    ushort_t* dbcb; ushort_t* dtb;
    __device__ void operator()(int z, int m, int n, float v) const {
        if (n < 32)
            dtb[(size_t)z*PADM_*32 + (size_t)m*32 + n] = f2bf(v);
        else if (n < 64)
            dbcb[(size_t)z*NT_*32 + (size_t)m*32 + (n-32)] = f2bf(v);
    }
};
struct EpiSpB {               // dt_proj: delta = softplus(v + bias) -> bf16
    ushort_t* C; const float* bias;
    __device__ void operator()(int z, int m, int n, float v) const {
        C[(size_t)z*NT_*DI_ + (size_t)m*DI_ + n] = f2bf(softplusf_(v + bias[z*DI_ + n]));
    }
};
struct EpiAcc {               // out_proj dir0: accumulate into residual
    float* C;
    __device__ void operator()(int, int m, int n, float v) const {
        C[(size_t)m*DM_ + n] += v;
    }
};
struct EpiAccFlipDual {       // out_proj dir1: flipped accumulate + bf16 residual copy
    float* C; ushort_t* Cb;
    __device__ void operator()(int, int m, int n, float v) const {
        int b = m / L_; int l = m - b*L_; int mm = b*L_ + (L_-1 - l);
        float o = C[(size_t)mm*DM_ + n] + v;
        C[(size_t)mm*DM_ + n] = o;
        Cb[(size_t)mm*DM_ + n] = f2bf(o);
    }
};
struct EpiHead {
    float* out; const float* bias; const float* mean; const float* stdv;
    const float* rw; const float* rb;
    __device__ void operator()(int z, int m, int n, float v) const {
        int b = m / CIN_, c = m - b*CIN_;
        float o = v + bias[n];
        o = (o - rb[c]) / (rw[c] + 1e-10f);
        o = o * stdv[m] + mean[m];
        out[((size_t)b*PRED_ + n)*CIN_ + c] = o;
    }
};

// ============================ bf16 MFMA GEMM (TN), z-batched, templated BK ============================
template<int BK, typename Epi>
__global__ __launch_bounds__(256) void gemm_bf16(const ushort_t* __restrict__ A, int lda, size_t zsa,
                                                 const ushort_t* __restrict__ Bw, int ldb, size_t zsb,
                                                 int M, int N, int K, Epi epi)
{
    __shared__ __align__(16) ushort_t As[128*BK];
    __shared__ __align__(16) ushort_t Bs[128*BK];
    const int z = blockIdx.z;
    A += (size_t)z*zsa; Bw += (size_t)z*zsb;
    const int tid  = threadIdx.x;
    const int m0 = blockIdx.x * 128, n0 = blockIdx.y * 128;
    const int wave = tid >> 6, lane = tid & 63;
    const int wm = (wave & 1) * 64, wn = (wave >> 1) * 64;
    const int ln16 = lane & 15, quad = lane >> 4;

    f32x4 acc[4][4] = {};

    if (BK == 64) {
        const int r8 = lane >> 3;
        const int colg = ((lane & 7) ^ r8) * 8;
        const ushort_t* Ag = A + (size_t)(m0 + wave*32 + r8)*lda + colg;
        const ushort_t* Bg = Bw + (size_t)(n0 + wave*32 + r8)*ldb + colg;
        ushort_t* AsW = As + wave*32*64;
        ushort_t* BsW = Bs + wave*32*64;
        for (int k0 = 0; k0 < K; k0 += 64) {
            #pragma unroll
            for (int j = 0; j < 4; ++j) {
                __builtin_amdgcn_global_load_lds((gbl_void_t*)(Ag + k0 + (size_t)(j*8)*lda),
                                                 (lds_void_t*)(AsW + j*8*64), 16, 0, 0);
                __builtin_amdgcn_global_load_lds((gbl_void_t*)(Bg + k0 + (size_t)(j*8)*ldb),
                                                 (lds_void_t*)(BsW + j*8*64), 16, 0, 0);
            }
            __syncthreads();
            #pragma unroll
            for (int ks = 0; ks < 2; ++ks) {
                bf16x8 af[4], bfr[4];
                #pragma unroll
                for (int i = 0; i < 4; ++i) {
                    int ra = wm + i*16 + ln16;
                    af[i]  = *(const bf16x8*)(As + ra*64 + (((ks*4 + quad) ^ (ra & 7)) * 8));
                    int rb2 = wn + i*16 + ln16;
                    bfr[i] = *(const bf16x8*)(Bs + rb2*64 + (((ks*4 + quad) ^ (rb2 & 7)) * 8));
                }
                #pragma unroll
                for (int mi = 0; mi < 4; ++mi)
                    #pragma unroll
                    for (int ni = 0; ni < 4; ++ni)
                        acc[mi][ni] = __builtin_amdgcn_mfma_f32_16x16x32_bf16(af[mi], bfr[ni], acc[mi][ni], 0, 0, 0);
            }
            __syncthreads();
        }
    } else {
        const int srow = lane >> 2, scol = (lane & 3) * 8;
        const ushort_t* Ag = A + (size_t)(m0 + wave*32 + srow)*lda + scol;
        const ushort_t* Bg = Bw + (size_t)(n0 + wave*32 + srow)*ldb + scol;
        ushort_t* AsW = As + wave*32*32;
        ushort_t* BsW = Bs + wave*32*32;
        for (int k0 = 0; k0 < K; k0 += 32) {
            __builtin_amdgcn_global_load_lds((gbl_void_t*)(Ag + k0),                  (lds_void_t*)AsW,           16, 0, 0);
            __builtin_amdgcn_global_load_lds((gbl_void_t*)(Ag + k0 + 16*(size_t)lda), (lds_void_t*)(AsW + 16*32), 16, 0, 0);
            __builtin_amdgcn_global_load_lds((gbl_void_t*)(Bg + k0),                  (lds_void_t*)BsW,           16, 0, 0);
            __builtin_amdgcn_global_load_lds((gbl_void_t*)(Bg + k0 + 16*(size_t)ldb), (lds_void_t*)(BsW + 16*32), 16, 0, 0);
            __syncthreads();
            bf16x8 af[4], bfr[4];
            #pragma unroll
            for (int i = 0; i < 4; ++i)
                af[i] = *(const bf16x8*)(As + (wm + i*16 + ln16)*32 + quad*8);
            #pragma unroll
            for (int i = 0; i < 4; ++i)
                bfr[i] = *(const bf16x8*)(Bs + (wn + i*16 + ln16)*32 + quad*8);
            #pragma unroll
            for (int mi = 0; mi < 4; ++mi)
                #pragma unroll
                for (int ni = 0; ni < 4; ++ni)
                    acc[mi][ni] = __builtin_amdgcn_mfma_f32_16x16x32_bf16(af[mi], bfr[ni], acc[mi][ni], 0, 0, 0);
            __syncthreads();
        }
    }

    #pragma unroll
    for (int mi = 0; mi < 4; ++mi) {
        #pragma unroll
        for (int r = 0; r < 4; ++r) {
            int m = m0 + wm + mi*16 + quad*4 + r;
            if (m >= M) continue;
            #pragma unroll
            for (int ni = 0; ni < 4; ++ni) {
                int n = n0 + wn + ni*16 + ln16;
                if (n < N) epi(z, m, n, acc[mi][ni][r]);
            }
        }
    }
}

// ============================ merged fp32 -> bf16 weight conversion ============================
struct CvtArgs {
    const float* src[7];
    ushort_t*    dst[7];
    int n4[7];
    int start[8];
};
__global__ __launch_bounds__(256) void cvt_all(CvtArgs a)
{
    int bid = blockIdx.x;
    int seg = 0;
    #pragma unroll
    for (int i = 0; i < 6; ++i) seg += (bid >= a.start[i+1]) ? 1 : 0;
    int idx = (bid - a.start[seg])*256 + threadIdx.x;
    if (idx < a.n4[seg]) {
        float4 v = ((const float4*)a.src[seg])[idx];
        ushort4 u; u.x=f2bf(v.x); u.y=f2bf(v.y); u.z=f2bf(v.z); u.w=f2bf(v.w);
        ((ushort4*)a.dst[seg])[idx] = u;
    }
}

// ============================ RevIN stats (parallel partials + finalize) ============================
__global__ __launch_bounds__(256) void revin_partial(const float* __restrict__ x,
                                                     float* __restrict__ psum,
                                                     float* __restrict__ psq)
{
    int b = blockIdx.x;
    int c0 = blockIdx.y * 64;
    int sz = blockIdx.z;
    int cl = threadIdx.x & 63;
    int sl = threadIdx.x >> 6;
    int c = c0 + cl;
    int s0 = sz * 64;
    float sum = 0.f, sq = 0.f;
    if (c < CIN_) {
        #pragma unroll
        for (int i = 0; i < 16; ++i) {
            int s = s0 + sl + i*4;
            float v = x[((size_t)b*SEQ_ + s)*CIN_ + c];
            sum += v; sq += v*v;
        }
    }
    __shared__ float ssum[4][64], ssq[4][64];
    ssum[sl][cl] = sum; ssq[sl][cl] = sq;
    __syncthreads();
    if (sl == 0 && c < CIN_) {
        float s = ssum[0][cl]+ssum[1][cl]+ssum[2][cl]+ssum[3][cl];
        float q = ssq[0][cl]+ssq[1][cl]+ssq[2][cl]+ssq[3][cl];
        psum[((size_t)b*8 + sz)*PS_ + c] = s;
        psq [((size_t)b*8 + sz)*PS_ + c] = q;
    }
}
__global__ __launch_bounds__(384) void revin_final(const float* __restrict__ psum,
                                                   const float* __restrict__ psq,
                                                   float* __restrict__ meanb,
                                                   float* __restrict__ stdb)
{
    int b = blockIdx.x;
    int c = threadIdx.x;
    if (c >= CIN_) return;
    float s = 0.f, q = 0.f;
    #pragma unroll
    for (int i = 0; i < 8; ++i) {
        s += psum[((size_t)b*8 + i)*PS_ + c];
        q += psq [((size_t)b*8 + i)*PS_ + c];
    }
    float mn = s * (1.f/SEQ_);
    float var = q * (1.f/SEQ_) - mn*mn;
    meanb[b*CIN_ + c] = mn;
    stdb[b*CIN_ + c]  = sqrtf(var + 1e-5f);
}

// ============================ normalize + transpose (writes bf16) ============================
__global__ __launch_bounds__(256) void norm_transpose(const float* __restrict__ x,
                                                      const float* __restrict__ meanb,
                                                      const float* __restrict__ stdb,
                                                      const float* __restrict__ rw,
                                                      const float* __restrict__ rb,
                                                      ushort_t* __restrict__ xt)
{
    __shared__ float tile[64][65];
    int b = blockIdx.x, s0 = blockIdx.y*64, c0 = blockIdx.z*64;
    int cl = threadIdx.x & 63, sl = threadIdx.x >> 6;
    #pragma unroll
    for (int i = 0; i < 16; ++i) {
        int s = s0 + sl + i*4;
        int c = c0 + cl;
        float v = 0.f;
        if (c < CIN_) v = x[((size_t)b*SEQ_ + s)*CIN_ + c];
        tile[sl + i*4][cl] = v;
    }
    __syncthreads();
    int sl2 = threadIdx.x & 63, cl2 = threadIdx.x >> 6;
    #pragma unroll
    for (int i = 0; i < 16; ++i) {
        int c = c0 + cl2 + i*4;
        if (c >= CIN_) continue;
        int m = b*CIN_ + c;
        float v = tile[sl2][cl2 + i*4];
        v = (v - meanb[m]) / stdb[m] * rw[c] + rb[c];
        xt[(size_t)m*SEQ_ + s0 + sl2] = f2bf(v);
    }
}

// ============================ depthwise causal conv + SiLU (vectorized: 4 ch/thread) ============================
__global__ __launch_bounds__(256) void conv_silu(const ushort_t* __restrict__ xzb,
                                                 const float* __restrict__ cw,
                                                 const float* __restrict__ cb,
                                                 ushort_t* __restrict__ xcb)
{
    int m = blockIdx.x;
    int im = blockIdx.y;
    int d4 = threadIdx.x * 4;
    const ushort_t* xz = xzb + (size_t)im*PADM_*2*DI_;
    int b = m / L_, l = m - b*L_;
    float wjt[4][4];
    #pragma unroll
    for (int j = 0; j < 4; ++j) {
        float4 w = ((const float4*)cw)[(size_t)im*DI_ + d4 + j];
        wjt[j][0]=w.x; wjt[j][1]=w.y; wjt[j][2]=w.z; wjt[j][3]=w.w;
    }
    float4 bb = *(const float4*)(cb + (size_t)im*DI_ + d4);
    float acc4[4] = {bb.x, bb.y, bb.z, bb.w};
    #pragma unroll
    for (int t = 0; t < 4; ++t) {
        int ls = l - 3 + t;
        if (ls >= 0) {
            ushort4 xv = *(const ushort4*)(xz + (size_t)(b*L_ + ls)*2*DI_ + d4);
            acc4[0] += bf2f(xv.x) * wjt[0][t];
            acc4[1] += bf2f(xv.y) * wjt[1][t];
            acc4[2] += bf2f(xv.z) * wjt[2][t];
            acc4[3] += bf2f(xv.w) * wjt[3][t];
        }
    }
    ushort4 o;
    o.x = f2bf(acc4[0] * sigmoidf_(acc4[0]));
    o.y = f2bf(acc4[1] * sigmoidf_(acc4[1]));
    o.z = f2bf(acc4[2] * sigmoidf_(acc4[2]));
    o.w = f2bf(acc4[3] * sigmoidf_(acc4[3]));
    *(ushort4*)(xcb + (size_t)im*PADM_*DI_ + (size_t)m*DI_ + d4) = o;
}

// ============================ chunked selective scan (pure f32x4 SSA; bf16 delta + bf16 B/C) ============================
// R14: dt-fold reverted (R13: dot-product re-spilled scan to 48 VGPR). B/C now bf16
// (wave-uniform broadcast loads, half the bytes).

__global__ __launch_bounds__(64, 1) void scan_p1(const ushort_t* __restrict__ dl,
                                                 const ushort_t* __restrict__ xcb,
                                                 const ushort_t* __restrict__ dbcb,
                                                 const float* __restrict__ A_log,
                                                 ushort_t* __restrict__ hloc,
                                                 float* __restrict__ Ssum)
{
    const int im = blockIdx.z >> 4, b = blockIdx.z & 15;
    const int c = blockIdx.y;
    const int d = blockIdx.x*64 + threadIdx.x;
    const ushort_t* dlz = dl + (size_t)im*NT_*DI_;
    const ushort_t* xcz = xcb + (size_t)im*PADM_*DI_;
    const ushort_t* dbz = dbcb + (size_t)im*NT_*32;

    const float* ar = A_log + ((size_t)im*DI_ + d)*NST_;
    f32x4 t0 = *(const f32x4*)(ar+0), t1 = *(const f32x4*)(ar+4);
    f32x4 t2 = *(const f32x4*)(ar+8), t3 = *(const f32x4*)(ar+12);
    f32x4 av0, av1, av2, av3;
    #pragma unroll
    for (int j = 0; j < 4; ++j) {
        av0[j] = -__expf(t0[j]); av1[j] = -__expf(t1[j]);
        av2[j] = -__expf(t2[j]); av3[j] = -__expf(t3[j]);
    }
    const float a0 = av0[0];
    bool uni = true;
    #pragma unroll
    for (int j = 0; j < 4; ++j) {
        uni = uni && (fabsf(av0[j] - (j+1)*a0)  <= 1e-3f*(j+1));
        uni = uni && (fabsf(av1[j] - (j+5)*a0)  <= 1e-3f*(j+5));
        uni = uni && (fabsf(av2[j] - (j+9)*a0)  <= 1e-3f*(j+9));
        uni = uni && (fabsf(av3[j] - (j+13)*a0) <= 1e-3f*(j+13));
    }

    const int t0i = c*TC_, tend = (t0i + TC_ < L_) ? t0i + TC_ : L_;
    f32x4 h0 = {0,0,0,0}, h1 = {0,0,0,0}, h2 = {0,0,0,0}, h3 = {0,0,0,0};
    float S = 0.f;
    if (uni) {
        for (int t = t0i; t < tend; ++t) {
            int tok = b*L_ + t;
            float dv = bf2f(dlz[(size_t)tok*DI_ + d]);
            float xv = bf2f(xcz[(size_t)tok*DI_ + d]);
            f32x4 Bv0 = bf4_to_f4(*(const ushort4*)(dbz + (size_t)tok*32 + 0));
            f32x4 Bv1 = bf4_to_f4(*(const ushort4*)(dbz + (size_t)tok*32 + 4));
            f32x4 Bv2 = bf4_to_f4(*(const ushort4*)(dbz + (size_t)tok*32 + 8));
            f32x4 Bv3 = bf4_to_f4(*(const ushort4*)(dbz + (size_t)tok*32 + 12));
            S += dv;
            float du = dv * xv;
            float e1 = __expf(dv * a0);
            float e2 = e1*e1, e4 = e2*e2;
            f32x4 dA = {e1, e2, e2*e1, e4};
            h0 = dA*h0 + du*Bv0;  dA = dA*e4;
            h1 = dA*h1 + du*Bv1;  dA = dA*e4;
            h2 = dA*h2 + du*Bv2;  dA = dA*e4;
            h3 = dA*h3 + du*Bv3;
        }
    } else {
        for (int t = t0i; t < tend; ++t) {
            int tok = b*L_ + t;
            float dv = bf2f(dlz[(size_t)tok*DI_ + d]);
            float xv = bf2f(xcz[(size_t)tok*DI_ + d]);
            f32x4 Bv0 = bf4_to_f4(*(const ushort4*)(dbz + (size_t)tok*32 + 0));
            f32x4 Bv1 = bf4_to_f4(*(const ushort4*)(dbz + (size_t)tok*32 + 4));
            f32x4 Bv2 = bf4_to_f4(*(const ushort4*)(dbz + (size_t)tok*32 + 8));
            f32x4 Bv3 = bf4_to_f4(*(const ushort4*)(dbz + (size_t)tok*32 + 12));
            S += dv;
            float du = dv * xv;
            f32x4 dA0, dA1, dA2, dA3;
            #pragma unroll
            for (int j = 0; j < 4; ++j) {
                dA0[j] = __expf(dv*av0[j]); dA1[j] = __expf(dv*av1[j]);
                dA2[j] = __expf(dv*av2[j]); dA3[j] = __expf(dv*av3[j]);
            }
            h0 = dA0*h0 + du*Bv0;
            h1 = dA1*h1 + du*Bv1;
            h2 = dA2*h2 + du*Bv2;
            h3 = dA3*h3 + du*Bv3;
        }
    }
    size_t base = ((size_t)(im*16 + b)*NC_ + c);
    Ssum[base*DI_ + d] = S;
    #pragma unroll
    for (int n = 0; n < 4; ++n) {
        hloc[(base*NST_ + n +  0)*DI_ + d] = f2bf(h0[n]);
        hloc[(base*NST_ + n +  4)*DI_ + d] = f2bf(h1[n]);
        hloc[(base*NST_ + n +  8)*DI_ + d] = f2bf(h2[n]);
        hloc[(base*NST_ + n + 12)*DI_ + d] = f2bf(h3[n]);
    }
}

__global__ __launch_bounds__(64, 1) void scan_p2(const ushort_t* __restrict__ dl,
                                                 const ushort_t* __restrict__ xcb,
                                                 ushort_t* __restrict__ xzb,
                                                 const ushort_t* __restrict__ dbcb,
                                                 const float* __restrict__ A_log,
                                                 const float* __restrict__ Dp,
                                                 const ushort_t* __restrict__ hloc,
                                                 const float* __restrict__ Ssum)
{
    const int im = blockIdx.z >> 4, b = blockIdx.z & 15;
    const int c = blockIdx.y;
    const int d = blockIdx.x*64 + threadIdx.x;
    const ushort_t* dlz = dl + (size_t)im*NT_*DI_;
    const ushort_t* xcz = xcb + (size_t)im*PADM_*DI_;
    const ushort_t* dbz = dbcb + (size_t)im*NT_*32;
    ushort_t* xzz = xzb + (size_t)im*PADM_*2*DI_;

    const float* ar = A_log + ((size_t)im*DI_ + d)*NST_;
    f32x4 t0 = *(const f32x4*)(ar+0), t1 = *(const f32x4*)(ar+4);
    f32x4 t2 = *(const f32x4*)(ar+8), t3 = *(const f32x4*)(ar+12);
    f32x4 av0, av1, av2, av3;
    #pragma unroll
    for (int j = 0; j < 4; ++j) {
        av0[j] = -__expf(t0[j]); av1[j] = -__expf(t1[j]);
        av2[j] = -__expf(t2[j]); av3[j] = -__expf(t3[j]);
    }
    const float a0 = av0[0];
    bool uni = true;
    #pragma unroll
    for (int j = 0; j < 4; ++j) {
        uni = uni && (fabsf(av0[j] - (j+1)*a0)  <= 1e-3f*(j+1));
        uni = uni && (fabsf(av1[j] - (j+5)*a0)  <= 1e-3f*(j+5));
        uni = uni && (fabsf(av2[j] - (j+9)*a0)  <= 1e-3f*(j+9));
        uni = uni && (fabsf(av3[j] - (j+13)*a0) <= 1e-3f*(j+13));
    }
    const float Dd = Dp[im*DI_ + d];
    const int t0i = c*TC_, tend = (t0i + TC_ < L_) ? t0i + TC_ : L_;
    const size_t gbase = (size_t)(im*16 + b)*NC_;

    // compose carry over chunks < c (hloc is bf16)
    f32x4 h0 = {0,0,0,0}, h1 = {0,0,0,0}, h2 = {0,0,0,0}, h3 = {0,0,0,0};
    for (int cc = 0; cc < c; ++cc) {
        size_t base2 = gbase + cc;
        float S = Ssum[base2*DI_ + d];
        f32x4 hl0, hl1, hl2, hl3;
        #pragma unroll
        for (int n = 0; n < 4; ++n) {
            hl0[n] = bf2f(hloc[(base2*NST_ + n +  0)*DI_ + d]);
            hl1[n] = bf2f(hloc[(base2*NST_ + n +  4)*DI_ + d]);
            hl2[n] = bf2f(hloc[(base2*NST_ + n +  8)*DI_ + d]);
            hl3[n] = bf2f(hloc[(base2*NST_ + n + 12)*DI_ + d]);
        }
        if (uni) {
            float eS = __expf(S * a0);
            float e2 = eS*eS, e4 = e2*e2;
            f32x4 f = {eS, e2, e2*eS, e4};
            h0 = f*h0 + hl0;  f = f*e4;
            h1 = f*h1 + hl1;  f = f*e4;
            h2 = f*h2 + hl2;  f = f*e4;
            h3 = f*h3 + hl3;
        } else {
            f32x4 f0, f1, f2v, f3;
            #pragma unroll
            for (int j = 0; j < 4; ++j) {
                f0[j] = __expf(S*av0[j]); f1[j] = __expf(S*av1[j]);
                f2v[j] = __expf(S*av2[j]); f3[j] = __expf(S*av3[j]);
            }
            h0 = f0*h0 + hl0; h1 = f1*h1 + hl1;
            h2 = f2v*h2 + hl2; h3 = f3*h3 + hl3;
        }
    }

    if (uni) {
        for (int t = t0i; t < tend; ++t) {
            int tok = b*L_ + t;
            float dv = bf2f(dlz[(size_t)tok*DI_ + d]);
            float xv = bf2f(xcz[(size_t)tok*DI_ + d]);
            f32x4 Bv0 = bf4_to_f4(*(const ushort4*)(dbz + (size_t)tok*32 + 0));
            f32x4 Bv1 = bf4_to_f4(*(const ushort4*)(dbz + (size_t)tok*32 + 4));
            f32x4 Bv2 = bf4_to_f4(*(const ushort4*)(dbz + (size_t)tok*32 + 8));
            f32x4 Bv3 = bf4_to_f4(*(const ushort4*)(dbz + (size_t)tok*32 + 12));
            f32x4 Cv0 = bf4_to_f4(*(const ushort4*)(dbz + (size_t)tok*32 + 16));
            f32x4 Cv1 = bf4_to_f4(*(const ushort4*)(dbz + (size_t)tok*32 + 20));
            f32x4 Cv2 = bf4_to_f4(*(const ushort4*)(dbz + (size_t)tok*32 + 24));
            f32x4 Cv3 = bf4_to_f4(*(const ushort4*)(dbz + (size_t)tok*32 + 28));
            float zg = bf2f(xzz[(size_t)tok*2*DI_ + DI_ + d]);
            float du = dv * xv;
            float e1 = __expf(dv * a0);
            float e2 = e1*e1, e4 = e2*e2;
            f32x4 dA = {e1, e2, e2*e1, e4};
            h0 = dA*h0 + du*Bv0;  dA = dA*e4;
            h1 = dA*h1 + du*Bv1;  dA = dA*e4;
            h2 = dA*h2 + du*Bv2;  dA = dA*e4;
            h3 = dA*h3 + du*Bv3;
            f32x4 yv = h0*Cv0 + h1*Cv1 + h2*Cv2 + h3*Cv3;
            float y = yv[0] + yv[1] + yv[2] + yv[3];
            y = (y + Dd*xv) * (zg * sigmoidf_(zg));
            xzz[(size_t)tok*2*DI_ + d] = f2bf(y);
        }
    } else {
        for (int t = t0i; t < tend; ++t) {
            int tok = b*L_ + t;
            float dv = bf2f(dlz[(size_t)tok*DI_ + d]);
            float xv = bf2f(xcz[(size_t)tok*DI_ + d]);
            f32x4 Bv0 = bf4_to_f4(*(const ushort4*)(dbz + (size_t)tok*32 + 0));
            f32x4 Bv1 = bf4_to_f4(*(const ushort4*)(dbz + (size_t)tok*32 + 4));
            f32x4 Bv2 = bf4_to_f4(*(const ushort4*)(dbz + (size_t)tok*32 + 8));
            f32x4 Bv3 = bf4_to_f4(*(const ushort4*)(dbz + (size_t)tok*32 + 12));
            f32x4 Cv0 = bf4_to_f4(*(const ushort4*)(dbz + (size_t)tok*32 + 16));
            f32x4 Cv1 = bf4_to_f4(*(const ushort4*)(dbz + (size_t)tok*32 + 20));
            f32x4 Cv2 = bf4_to_f4(*(const ushort4*)(dbz + (size_t)tok*32 + 24));
            f32x4 Cv3 = bf4_to_f4(*(const ushort4*)(dbz + (size_t)tok*32 + 28));
            float zg = bf2f(xzz[(size_t)tok*2*DI_ + DI_ + d]);
            float du = dv * xv;
            f32x4 dA0, dA1, dA2, dA3;
            #pragma unroll
            for (int j = 0; j < 4; ++j) {
                dA0[j] = __expf(dv*av0[j]); dA1[j] = __expf(dv*av1[j]);
                dA2[j] = __expf(dv*av2[j]); dA3[j] = __expf(dv*av3[j]);
            }
            h0 = dA0*h0 + du*Bv0;
            h1 = dA1*h1 + du*Bv1;
            h2 = dA2*h2 + du*Bv2;
            h3 = dA3*h3 + du*Bv3;
            f32x4 yv = h0*Cv0 + h1*Cv1 + h2*Cv2 + h3*Cv3;
            float y = yv[0] + yv[1] + yv[2] + yv[3];
            y = (y + Dd*xv) * (zg * sigmoidf_(zg));
            xzz[(size_t)tok*2*DI_ + d] = f2bf(y);
        }
    }
}

// ============================ launch ============================
extern "C" void kernel_launch(void* const* d_in, const int* in_sizes, int n_in,
                              void* d_out, int out_size, void* d_ws, size_t ws_size,
                              hipStream_t stream)
{
    const float* x      = (const float*)d_in[0];
    const float* rw     = (const float*)d_in[1];
    const float* rb     = (const float*)d_in[2];
    const float* lin1_w = (const float*)d_in[3];
    const float* lin1_b = (const float*)d_in[4];
    const float* head_w = (const float*)d_in[5];
    const float* head_b = (const float*)d_in[6];
    const float* ipw    = (const float*)d_in[7];
    const float* cw     = (const float*)d_in[8];
    const float* cb     = (const float*)d_in[9];
    const float* xpw    = (const float*)d_in[10];
    const float* dpw    = (const float*)d_in[11];
    const float* dpb    = (const float*)d_in[12];
    const float* A_log  = (const float*)d_in[13];
    const float* Dp     = (const float*)d_in[14];
    const float* opw    = (const float*)d_in[15];
    float* out = (float*)d_out;

    float* ws = (float*)d_ws;
    size_t off = 0;
    auto alloc = [&](size_t nfloats) { float* p = ws + off; off += (nfloats + 63) & ~(size_t)63; return p; };
    float* meanb = alloc(NT_);
    float* stdb  = alloc(NT_);
    float* psum  = alloc((size_t)B_*8*PS_);
    float* psq   = alloc((size_t)B_*8*PS_);
    ushort_t* xnt_bf = (ushort_t*)alloc((size_t)PADM_*SEQ_/2);
    ushort_t* tbf    = (ushort_t*)alloc((size_t)PADM_*DM_/2);
    float* tres  = alloc((size_t)NT_*DM_);
    ushort_t* xzb = (ushort_t*)alloc((size_t)2*PADM_*2*DI_/2);
    ushort_t* xcb = (ushort_t*)alloc((size_t)2*PADM_*DI_/2);
    ushort_t* dlb = (ushort_t*)alloc((size_t)2*NT_*DI_/2);        // bf16 delta
    ushort_t* dbcb = (ushort_t*)alloc((size_t)2*NT_*32/2);        // bf16 B/C
    ushort_t* dtb = (ushort_t*)alloc((size_t)2*PADM_*32/2);       // bf16 dt
    ushort_t* hloc = (ushort_t*)alloc((size_t)2*16*NC_*NST_*DI_/2);
    float* Ssum  = alloc((size_t)2*16*NC_*DI_);
    ushort_t* lin1_bf = (ushort_t*)alloc((size_t)DM_*SEQ_/2);
    ushort_t* head_bf = (ushort_t*)alloc((size_t)128*DM_/2);
    ushort_t* ipw_bf  = (ushort_t*)alloc((size_t)2*2*DI_*DM_/2);
    ushort_t* opw_bf  = (ushort_t*)alloc((size_t)2*DM_*DI_/2);
    ushort_t* xpw_bf  = (ushort_t*)alloc((size_t)2*128*DI_/2);
    ushort_t* dpw_bf  = (ushort_t*)alloc((size_t)2*DI_*RNK_/2);
    (void)ws_size; (void)in_sizes; (void)n_in; (void)out_size;

    dim3 blk(256);

    CvtArgs ca;
    const float* srcs[7] = {lin1_w, head_w, ipw, opw, dpw, xpw, xpw + 64*DI_};
    ushort_t*    dsts[7] = {lin1_bf, head_bf, ipw_bf, opw_bf, dpw_bf, xpw_bf, xpw_bf + 128*DI_};
    int ns[7] = {DM_*SEQ_, PRED_*DM_, 2*2*DI_*DM_, 2*DM_*DI_, 2*DI_*RNK_, 64*DI_, 64*DI_};
    ca.start[0] = 0;
    for (int i = 0; i < 7; ++i) {
        ca.src[i] = srcs[i]; ca.dst[i] = dsts[i]; ca.n4[i] = ns[i]/4;
        ca.start[i+1] = ca.start[i] + (ca.n4[i] + 255)/256;
    }
    cvt_all<<<dim3(ca.start[7]), blk, 0, stream>>>(ca);

    revin_partial<<<dim3(B_, 6, 8), blk, 0, stream>>>(x, psum, psq);
    revin_final<<<dim3(B_), dim3(384), 0, stream>>>(psum, psq, meanb, stdb);
    norm_transpose<<<dim3(B_, 8, 6), blk, 0, stream>>>(x, meanb, stdb, rw, rb, xnt_bf);
    gemm_bf16<64><<<dim3(41, 4, 1), blk, 0, stream>>>(xnt_bf, SEQ_, 0, lin1_bf, SEQ_, 0,
                                                      NT_, DM_, SEQ_,
                                                      EpiBiasDual{tres, tbf, lin1_b});

    for (int layer = 0; layer < 2; ++layer) {
        // in_proj, both dirs merged into one N=4096 GEMM (dir = n>>11 in epilogue)
        gemm_bf16<64><<<dim3(41, 32, 1), blk, 0, stream>>>(
            tbf, DM_, 0, ipw_bf, DM_, 0,
            NT_, 2*2*DI_, DM_, EpiXZ2{xzb});
        conv_silu<<<dim3(NT_, 2), blk, 0, stream>>>(xzb, cw, cb, xcb);
        // x_proj (both dirs): dt -> bf16 dtb, B/C -> bf16 dbcb
        gemm_bf16<64><<<dim3(41, 1, 2), blk, 0, stream>>>(
            xcb, DI_, (size_t)PADM_*DI_, xpw_bf, DI_, (size_t)128*DI_,
            NT_, 64, DI_, EpiDbl{dbcb, dtb});
        // delta (both dirs): softplus(dt @ dpw^T + dpb) -> bf16   [MFMA K=32]
        gemm_bf16<32><<<dim3(41, 8, 2), blk, 0, stream>>>(
            dtb, 32, (size_t)PADM_*32, dpw_bf, 32, (size_t)DI_*RNK_,
            NT_, DI_, RNK_, EpiSpB{dlb, dpb});
        // chunked scan (both dirs); p2 composes carries inline
        scan_p1<<<dim3(16, NC_-1, 32), dim3(64), 0, stream>>>(dlb, xcb, dbcb, A_log, hloc, Ssum);
        scan_p2<<<dim3(16, NC_, 32), dim3(64), 0, stream>>>(dlb, xcb, xzb, dbcb, A_log, Dp, hloc, Ssum);
        // out_proj: dir0 accumulates into residual; dir1 flipped-accumulate + bf16 copy
        gemm_bf16<64><<<dim3(41, 4, 1), blk, 0, stream>>>(
            xzb, 2*DI_, 0, opw_bf, DI_, 0,
            NT_, DM_, DI_, EpiAcc{tres});
        gemm_bf16<64><<<dim3(41, 4, 1), blk, 0, stream>>>(
            xzb + (size_t)PADM_*2*DI_, 2*DI_, 0, opw_bf + (size_t)DM_*DI_, DI_, 0,
            NT_, DM_, DI_, EpiAccFlipDual{tres, tbf});
    }
    gemm_bf16<64><<<dim3(41, 1, 1), blk, 0, stream>>>(tbf, DM_, 0, head_bf, DM_, 0,
                                                      NT_, PRED_, DM_,
                                                      EpiHead{out, head_b, meanb, stdb, rw, rb});
}

// Round 15
// 571.400 us; speedup vs baseline: 1.1574x; 1.1574x over previous
//
#include <hip/hip_runtime.h>
#include <hip/hip_bf16.h>
#include <cstdint>
#include <cstddef>

#define B_    16
#define SEQ_  512
#define CIN_  321
#define PRED_ 96
#define DM_   512
#define DI_   1024
#define NST_  16
#define RNK_  32
#define L_    321
#define NT_   (B_*CIN_)   // 5136 tokens
#define PADM_ 5248        // NT_ padded to multiple of 128 for OOB-safe tile reads
#define TC_   41          // scan chunk length (8 chunks: 7x41 + 34)
#define NC_   8
#define PS_   384         // padded CIN for stats partials

typedef unsigned short ushort_t;
typedef __bf16 bf16x8 __attribute__((ext_vector_type(8)));
typedef float  f32x4  __attribute__((ext_vector_type(4)));
typedef __attribute__((address_space(3))) void lds_void_t;
typedef const __attribute__((address_space(1))) void gbl_void_t;

__device__ __forceinline__ float sigmoidf_(float x){ return 1.f/(1.f+__expf(-x)); }
__device__ __forceinline__ float softplusf_(float x){
    return (x > 15.f) ? x : __logf(1.f + __expf(x));
}
__device__ __forceinline__ ushort_t f2bf(float f){
    union { float f; unsigned u; } v; v.f = f;
    unsigned r = v.u + 0x7FFF + ((v.u >> 16) & 1);
    return (ushort_t)(r >> 16);
}
__device__ __forceinline__ float bf2f(ushort_t u){
    return __uint_as_float(((unsigned)u) << 16);
}
__device__ __forceinline__ f32x4 bf4_to_f4(ushort4 u){
    f32x4 r; r[0]=bf2f(u.x); r[1]=bf2f(u.y); r[2]=bf2f(u.z); r[3]=bf2f(u.w);
    return r;
}

// ============================ epilogues (z-batched: epi(z,m,n,v)) ============================
struct EpiBiasDual {          // embed: fp32 residual + bf16 copy
    float* C; ushort_t* Cb; const float* bias;
    __device__ void operator()(int z, int m, int n, float v) const {
        float o = v + bias[n];
        C[(size_t)m*DM_ + n] = o;
        Cb[(size_t)m*DM_ + n] = f2bf(o);
    }
};
struct EpiXZ2 {               // merged-dir in_proj: N=4096, dir = n>>11; z=1 rows flipped
    ushort_t* xzb;
    __device__ void operator()(int, int m, int n, float v) const {
        int z = n >> 11, nn = n & 2047;
        int mm = m;
        if (z) { int b = m / L_; int l = m - b*L_; mm = b*L_ + (L_-1 - l); }
        xzb[(size_t)z*PADM_*2*DI_ + (size_t)mm*(2*DI_) + nn] = f2bf(v);
    }
};
struct EpiDbl {               // x_proj: dt (n<32) -> bf16 dtb; B/C (32<=n<64) -> bf16 dbcb
    ushort_t* dbcb; ushort_t* dtb;
    __device__ void operator()(int z, int m, int n, float v) const {
        if (n < 32)
            dtb[(size_t)z*PADM_*32 + (size_t)m*32 + n] = f2bf(v);
        else if (n < 64)
            dbcb[(size_t)z*NT_*32 + (size_t)m*32 + (n-32)] = f2bf(v);
    }
};
struct EpiSpB {               // dt_proj: delta = softplus(v + bias) -> bf16
    ushort_t* C; const float* bias;
    __device__ void operator()(int z, int m, int n, float v) const {
        C[(size_t)z*NT_*DI_ + (size_t)m*DI_ + n] = f2bf(softplusf_(v + bias[z*DI_ + n]));
    }
};
struct EpiP {                 // out_proj: bf16 partial into P[z]
    ushort_t* P;
    __device__ void operator()(int z, int m, int n, float v) const {
        P[(size_t)z*NT_*DM_ + (size_t)m*DM_ + n] = f2bf(v);
    }
};
struct EpiHead {
    float* out; const float* bias; const float* mean; const float* stdv;
    const float* rw; const float* rb;
    __device__ void operator()(int z, int m, int n, float v) const {
        int b = m / CIN_, c = m - b*CIN_;
        float o = v + bias[n];
        o = (o - rb[c]) / (rw[c] + 1e-10f);
        o = o * stdv[m] + mean[m];
        out[((size_t)b*PRED_ + n)*CIN_ + c] = o;
    }
};

// ============================ bf16 MFMA GEMM (TN), z-batched, templated BK ============================
template<int BK, typename Epi>
__global__ __launch_bounds__(256) void gemm_bf16(const ushort_t* __restrict__ A, int lda, size_t zsa,
                                                 const ushort_t* __restrict__ Bw, int ldb, size_t zsb,
                                                 int M, int N, int K, Epi epi)
{
    __shared__ __align__(16) ushort_t As[128*BK];
    __shared__ __align__(16) ushort_t Bs[128*BK];
    const int z = blockIdx.z;
    A += (size_t)z*zsa; Bw += (size_t)z*zsb;
    const int tid  = threadIdx.x;
    const int m0 = blockIdx.x * 128, n0 = blockIdx.y * 128;
    const int wave = tid >> 6, lane = tid & 63;
    const int wm = (wave & 1) * 64, wn = (wave >> 1) * 64;
    const int ln16 = lane & 15, quad = lane >> 4;

    f32x4 acc[4][4] = {};

    if (BK == 64) {
        const int r8 = lane >> 3;
        const int colg = ((lane & 7) ^ r8) * 8;
        const ushort_t* Ag = A + (size_t)(m0 + wave*32 + r8)*lda + colg;
        const ushort_t* Bg = Bw + (size_t)(n0 + wave*32 + r8)*ldb + colg;
        ushort_t* AsW = As + wave*32*64;
        ushort_t* BsW = Bs + wave*32*64;
        for (int k0 = 0; k0 < K; k0 += 64) {
            #pragma unroll
            for (int j = 0; j < 4; ++j) {
                __builtin_amdgcn_global_load_lds((gbl_void_t*)(Ag + k0 + (size_t)(j*8)*lda),
                                                 (lds_void_t*)(AsW + j*8*64), 16, 0, 0);
                __builtin_amdgcn_global_load_lds((gbl_void_t*)(Bg + k0 + (size_t)(j*8)*ldb),
                                                 (lds_void_t*)(BsW + j*8*64), 16, 0, 0);
            }
            __syncthreads();
            #pragma unroll
            for (int ks = 0; ks < 2; ++ks) {
                bf16x8 af[4], bfr[4];
                #pragma unroll
                for (int i = 0; i < 4; ++i) {
                    int ra = wm + i*16 + ln16;
                    af[i]  = *(const bf16x8*)(As + ra*64 + (((ks*4 + quad) ^ (ra & 7)) * 8));
                    int rb2 = wn + i*16 + ln16;
                    bfr[i] = *(const bf16x8*)(Bs + rb2*64 + (((ks*4 + quad) ^ (rb2 & 7)) * 8));
                }
                #pragma unroll
                for (int mi = 0; mi < 4; ++mi)
                    #pragma unroll
                    for (int ni = 0; ni < 4; ++ni)
                        acc[mi][ni] = __builtin_amdgcn_mfma_f32_16x16x32_bf16(af[mi], bfr[ni], acc[mi][ni], 0, 0, 0);
            }
            __syncthreads();
        }
    } else {
        const int srow = lane >> 2, scol = (lane & 3) * 8;
        const ushort_t* Ag = A + (size_t)(m0 + wave*32 + srow)*lda + scol;
        const ushort_t* Bg = Bw + (size_t)(n0 + wave*32 + srow)*ldb + scol;
        ushort_t* AsW = As + wave*32*32;
        ushort_t* BsW = Bs + wave*32*32;
        for (int k0 = 0; k0 < K; k0 += 32) {
            __builtin_amdgcn_global_load_lds((gbl_void_t*)(Ag + k0),                  (lds_void_t*)AsW,           16, 0, 0);
            __builtin_amdgcn_global_load_lds((gbl_void_t*)(Ag + k0 + 16*(size_t)lda), (lds_void_t*)(AsW + 16*32), 16, 0, 0);
            __builtin_amdgcn_global_load_lds((gbl_void_t*)(Bg + k0),                  (lds_void_t*)BsW,           16, 0, 0);
            __builtin_amdgcn_global_load_lds((gbl_void_t*)(Bg + k0 + 16*(size_t)ldb), (lds_void_t*)(BsW + 16*32), 16, 0, 0);
            __syncthreads();
            bf16x8 af[4], bfr[4];
            #pragma unroll
            for (int i = 0; i < 4; ++i)
                af[i] = *(const bf16x8*)(As + (wm + i*16 + ln16)*32 + quad*8);
            #pragma unroll
            for (int i = 0; i < 4; ++i)
                bfr[i] = *(const bf16x8*)(Bs + (wn + i*16 + ln16)*32 + quad*8);
            #pragma unroll
            for (int mi = 0; mi < 4; ++mi)
                #pragma unroll
                for (int ni = 0; ni < 4; ++ni)
                    acc[mi][ni] = __builtin_amdgcn_mfma_f32_16x16x32_bf16(af[mi], bfr[ni], acc[mi][ni], 0, 0, 0);
            __syncthreads();
        }
    }

    #pragma unroll
    for (int mi = 0; mi < 4; ++mi) {
        #pragma unroll
        for (int r = 0; r < 4; ++r) {
            int m = m0 + wm + mi*16 + quad*4 + r;
            if (m >= M) continue;
            #pragma unroll
            for (int ni = 0; ni < 4; ++ni) {
                int n = n0 + wn + ni*16 + ln16;
                if (n < N) epi(z, m, n, acc[mi][ni][r]);
            }
        }
    }
}

// ============================ merged fp32 -> bf16 weight conversion ============================
struct CvtArgs {
    const float* src[7];
    ushort_t*    dst[7];
    int n4[7];
    int start[8];
};
__global__ __launch_bounds__(256) void cvt_all(CvtArgs a)
{
    int bid = blockIdx.x;
    int seg = 0;
    #pragma unroll
    for (int i = 0; i < 6; ++i) seg += (bid >= a.start[i+1]) ? 1 : 0;
    int idx = (bid - a.start[seg])*256 + threadIdx.x;
    if (idx < a.n4[seg]) {
        float4 v = ((const float4*)a.src[seg])[idx];
        ushort4 u; u.x=f2bf(v.x); u.y=f2bf(v.y); u.z=f2bf(v.z); u.w=f2bf(v.w);
        ((ushort4*)a.dst[seg])[idx] = u;
    }
}

// ============================ RevIN stats (parallel partials + finalize) ============================
__global__ __launch_bounds__(256) void revin_partial(const float* __restrict__ x,
                                                     float* __restrict__ psum,
                                                     float* __restrict__ psq)
{
    int b = blockIdx.x;
    int c0 = blockIdx.y * 64;
    int sz = blockIdx.z;
    int cl = threadIdx.x & 63;
    int sl = threadIdx.x >> 6;
    int c = c0 + cl;
    int s0 = sz * 64;
    float sum = 0.f, sq = 0.f;
    if (c < CIN_) {
        #pragma unroll
        for (int i = 0; i < 16; ++i) {
            int s = s0 + sl + i*4;
            float v = x[((size_t)b*SEQ_ + s)*CIN_ + c];
            sum += v; sq += v*v;
        }
    }
    __shared__ float ssum[4][64], ssq[4][64];
    ssum[sl][cl] = sum; ssq[sl][cl] = sq;
    __syncthreads();
    if (sl == 0 && c < CIN_) {
        float s = ssum[0][cl]+ssum[1][cl]+ssum[2][cl]+ssum[3][cl];
        float q = ssq[0][cl]+ssq[1][cl]+ssq[2][cl]+ssq[3][cl];
        psum[((size_t)b*8 + sz)*PS_ + c] = s;
        psq [((size_t)b*8 + sz)*PS_ + c] = q;
    }
}
__global__ __launch_bounds__(384) void revin_final(const float* __restrict__ psum,
                                                   const float* __restrict__ psq,
                                                   float* __restrict__ meanb,
                                                   float* __restrict__ stdb)
{
    int b = blockIdx.x;
    int c = threadIdx.x;
    if (c >= CIN_) return;
    float s = 0.f, q = 0.f;
    #pragma unroll
    for (int i = 0; i < 8; ++i) {
        s += psum[((size_t)b*8 + i)*PS_ + c];
        q += psq [((size_t)b*8 + i)*PS_ + c];
    }
    float mn = s * (1.f/SEQ_);
    float var = q * (1.f/SEQ_) - mn*mn;
    meanb[b*CIN_ + c] = mn;
    stdb[b*CIN_ + c]  = sqrtf(var + 1e-5f);
}

// ============================ normalize + transpose (writes bf16) ============================
__global__ __launch_bounds__(256) void norm_transpose(const float* __restrict__ x,
                                                      const float* __restrict__ meanb,
                                                      const float* __restrict__ stdb,
                                                      const float* __restrict__ rw,
                                                      const float* __restrict__ rb,
                                                      ushort_t* __restrict__ xt)
{
    __shared__ float tile[64][65];
    int b = blockIdx.x, s0 = blockIdx.y*64, c0 = blockIdx.z*64;
    int cl = threadIdx.x & 63, sl = threadIdx.x >> 6;
    #pragma unroll
    for (int i = 0; i < 16; ++i) {
        int s = s0 + sl + i*4;
        int c = c0 + cl;
        float v = 0.f;
        if (c < CIN_) v = x[((size_t)b*SEQ_ + s)*CIN_ + c];
        tile[sl + i*4][cl] = v;
    }
    __syncthreads();
    int sl2 = threadIdx.x & 63, cl2 = threadIdx.x >> 6;
    #pragma unroll
    for (int i = 0; i < 16; ++i) {
        int c = c0 + cl2 + i*4;
        if (c >= CIN_) continue;
        int m = b*CIN_ + c;
        float v = tile[sl2][cl2 + i*4];
        v = (v - meanb[m]) / stdb[m] * rw[c] + rb[c];
        xt[(size_t)m*SEQ_ + s0 + sl2] = f2bf(v);
    }
}

// ============================ depthwise causal conv + SiLU (vectorized: 4 ch/thread) ============================
__global__ __launch_bounds__(256) void conv_silu(const ushort_t* __restrict__ xzb,
                                                 const float* __restrict__ cw,
                                                 const float* __restrict__ cb,
                                                 ushort_t* __restrict__ xcb)
{
    int m = blockIdx.x;
    int im = blockIdx.y;
    int d4 = threadIdx.x * 4;
    const ushort_t* xz = xzb + (size_t)im*PADM_*2*DI_;
    int b = m / L_, l = m - b*L_;
    float wjt[4][4];
    #pragma unroll
    for (int j = 0; j < 4; ++j) {
        float4 w = ((const float4*)cw)[(size_t)im*DI_ + d4 + j];
        wjt[j][0]=w.x; wjt[j][1]=w.y; wjt[j][2]=w.z; wjt[j][3]=w.w;
    }
    float4 bb = *(const float4*)(cb + (size_t)im*DI_ + d4);
    float acc4[4] = {bb.x, bb.y, bb.z, bb.w};
    #pragma unroll
    for (int t = 0; t < 4; ++t) {
        int ls = l - 3 + t;
        if (ls >= 0) {
            ushort4 xv = *(const ushort4*)(xz + (size_t)(b*L_ + ls)*2*DI_ + d4);
            acc4[0] += bf2f(xv.x) * wjt[0][t];
            acc4[1] += bf2f(xv.y) * wjt[1][t];
            acc4[2] += bf2f(xv.z) * wjt[2][t];
            acc4[3] += bf2f(xv.w) * wjt[3][t];
        }
    }
    ushort4 o;
    o.x = f2bf(acc4[0] * sigmoidf_(acc4[0]));
    o.y = f2bf(acc4[1] * sigmoidf_(acc4[1]));
    o.z = f2bf(acc4[2] * sigmoidf_(acc4[2]));
    o.w = f2bf(acc4[3] * sigmoidf_(acc4[3]));
    *(ushort4*)(xcb + (size_t)im*PADM_*DI_ + (size_t)m*DI_ + d4) = o;
}

// ============================ chunked selective scan (pure f32x4 SSA; bf16 delta + bf16 B/C) ============================
__global__ __launch_bounds__(64, 1) void scan_p1(const ushort_t* __restrict__ dl,
                                                 const ushort_t* __restrict__ xcb,
                                                 const ushort_t* __restrict__ dbcb,
                                                 const float* __restrict__ A_log,
                                                 ushort_t* __restrict__ hloc,
                                                 float* __restrict__ Ssum)
{
    const int im = blockIdx.z >> 4, b = blockIdx.z & 15;
    const int c = blockIdx.y;
    const int d = blockIdx.x*64 + threadIdx.x;
    const ushort_t* dlz = dl + (size_t)im*NT_*DI_;
    const ushort_t* xcz = xcb + (size_t)im*PADM_*DI_;
    const ushort_t* dbz = dbcb + (size_t)im*NT_*32;

    const float* ar = A_log + ((size_t)im*DI_ + d)*NST_;
    f32x4 t0 = *(const f32x4*)(ar+0), t1 = *(const f32x4*)(ar+4);
    f32x4 t2 = *(const f32x4*)(ar+8), t3 = *(const f32x4*)(ar+12);
    f32x4 av0, av1, av2, av3;
    #pragma unroll
    for (int j = 0; j < 4; ++j) {
        av0[j] = -__expf(t0[j]); av1[j] = -__expf(t1[j]);
        av2[j] = -__expf(t2[j]); av3[j] = -__expf(t3[j]);
    }
    const float a0 = av0[0];
    bool uni = true;
    #pragma unroll
    for (int j = 0; j < 4; ++j) {
        uni = uni && (fabsf(av0[j] - (j+1)*a0)  <= 1e-3f*(j+1));
        uni = uni && (fabsf(av1[j] - (j+5)*a0)  <= 1e-3f*(j+5));
        uni = uni && (fabsf(av2[j] - (j+9)*a0)  <= 1e-3f*(j+9));
        uni = uni && (fabsf(av3[j] - (j+13)*a0) <= 1e-3f*(j+13));
    }

    const int t0i = c*TC_, tend = (t0i + TC_ < L_) ? t0i + TC_ : L_;
    f32x4 h0 = {0,0,0,0}, h1 = {0,0,0,0}, h2 = {0,0,0,0}, h3 = {0,0,0,0};
    float S = 0.f;
    if (uni) {
        for (int t = t0i; t < tend; ++t) {
            int tok = b*L_ + t;
            float dv = bf2f(dlz[(size_t)tok*DI_ + d]);
            float xv = bf2f(xcz[(size_t)tok*DI_ + d]);
            f32x4 Bv0 = bf4_to_f4(*(const ushort4*)(dbz + (size_t)tok*32 + 0));
            f32x4 Bv1 = bf4_to_f4(*(const ushort4*)(dbz + (size_t)tok*32 + 4));
            f32x4 Bv2 = bf4_to_f4(*(const ushort4*)(dbz + (size_t)tok*32 + 8));
            f32x4 Bv3 = bf4_to_f4(*(const ushort4*)(dbz + (size_t)tok*32 + 12));
            S += dv;
            float du = dv * xv;
            float e1 = __expf(dv * a0);
            float e2 = e1*e1, e4 = e2*e2;
            f32x4 dA = {e1, e2, e2*e1, e4};
            h0 = dA*h0 + du*Bv0;  dA = dA*e4;
            h1 = dA*h1 + du*Bv1;  dA = dA*e4;
            h2 = dA*h2 + du*Bv2;  dA = dA*e4;
            h3 = dA*h3 + du*Bv3;
        }
    } else {
        for (int t = t0i; t < tend; ++t) {
            int tok = b*L_ + t;
            float dv = bf2f(dlz[(size_t)tok*DI_ + d]);
            float xv = bf2f(xcz[(size_t)tok*DI_ + d]);
            f32x4 Bv0 = bf4_to_f4(*(const ushort4*)(dbz + (size_t)tok*32 + 0));
            f32x4 Bv1 = bf4_to_f4(*(const ushort4*)(dbz + (size_t)tok*32 + 4));
            f32x4 Bv2 = bf4_to_f4(*(const ushort4*)(dbz + (size_t)tok*32 + 8));
            f32x4 Bv3 = bf4_to_f4(*(const ushort4*)(dbz + (size_t)tok*32 + 12));
            S += dv;
            float du = dv * xv;
            f32x4 dA0, dA1, dA2, dA3;
            #pragma unroll
            for (int j = 0; j < 4; ++j) {
                dA0[j] = __expf(dv*av0[j]); dA1[j] = __expf(dv*av1[j]);
                dA2[j] = __expf(dv*av2[j]); dA3[j] = __expf(dv*av3[j]);
            }
            h0 = dA0*h0 + du*Bv0;
            h1 = dA1*h1 + du*Bv1;
            h2 = dA2*h2 + du*Bv2;
            h3 = dA3*h3 + du*Bv3;
        }
    }
    size_t base = ((size_t)(im*16 + b)*NC_ + c);
    Ssum[base*DI_ + d] = S;
    #pragma unroll
    for (int n = 0; n < 4; ++n) {
        hloc[(base*NST_ + n +  0)*DI_ + d] = f2bf(h0[n]);
        hloc[(base*NST_ + n +  4)*DI_ + d] = f2bf(h1[n]);
        hloc[(base*NST_ + n +  8)*DI_ + d] = f2bf(h2[n]);
        hloc[(base*NST_ + n + 12)*DI_ + d] = f2bf(h3[n]);
    }
}

__global__ __launch_bounds__(64, 1) void scan_p2(const ushort_t* __restrict__ dl,
                                                 const ushort_t* __restrict__ xcb,
                                                 ushort_t* __restrict__ xzb,
                                                 const ushort_t* __restrict__ dbcb,
                                                 const float* __restrict__ A_log,
                                                 const float* __restrict__ Dp,
                                                 const ushort_t* __restrict__ hloc,
                                                 const float* __restrict__ Ssum)
{
    const int im = blockIdx.z >> 4, b = blockIdx.z & 15;
    const int c = blockIdx.y;
    const int d = blockIdx.x*64 + threadIdx.x;
    const ushort_t* dlz = dl + (size_t)im*NT_*DI_;
    const ushort_t* xcz = xcb + (size_t)im*PADM_*DI_;
    const ushort_t* dbz = dbcb + (size_t)im*NT_*32;
    ushort_t* xzz = xzb + (size_t)im*PADM_*2*DI_;

    const float* ar = A_log + ((size_t)im*DI_ + d)*NST_;
    f32x4 t0 = *(const f32x4*)(ar+0), t1 = *(const f32x4*)(ar+4);
    f32x4 t2 = *(const f32x4*)(ar+8), t3 = *(const f32x4*)(ar+12);
    f32x4 av0, av1, av2, av3;
    #pragma unroll
    for (int j = 0; j < 4; ++j) {
        av0[j] = -__expf(t0[j]); av1[j] = -__expf(t1[j]);
        av2[j] = -__expf(t2[j]); av3[j] = -__expf(t3[j]);
    }
    const float a0 = av0[0];
    bool uni = true;
    #pragma unroll
    for (int j = 0; j < 4; ++j) {
        uni = uni && (fabsf(av0[j] - (j+1)*a0)  <= 1e-3f*(j+1));
        uni = uni && (fabsf(av1[j] - (j+5)*a0)  <= 1e-3f*(j+5));
        uni = uni && (fabsf(av2[j] - (j+9)*a0)  <= 1e-3f*(j+9));
        uni = uni && (fabsf(av3[j] - (j+13)*a0) <= 1e-3f*(j+13));
    }
    const float Dd = Dp[im*DI_ + d];
    const int t0i = c*TC_, tend = (t0i + TC_ < L_) ? t0i + TC_ : L_;
    const size_t gbase = (size_t)(im*16 + b)*NC_;

    f32x4 h0 = {0,0,0,0}, h1 = {0,0,0,0}, h2 = {0,0,0,0}, h3 = {0,0,0,0};
    for (int cc = 0; cc < c; ++cc) {
        size_t base2 = gbase + cc;
        float S = Ssum[base2*DI_ + d];
        f32x4 hl0, hl1, hl2, hl3;
        #pragma unroll
        for (int n = 0; n < 4; ++n) {
            hl0[n] = bf2f(hloc[(base2*NST_ + n +  0)*DI_ + d]);
            hl1[n] = bf2f(hloc[(base2*NST_ + n +  4)*DI_ + d]);
            hl2[n] = bf2f(hloc[(base2*NST_ + n +  8)*DI_ + d]);
            hl3[n] = bf2f(hloc[(base2*NST_ + n + 12)*DI_ + d]);
        }
        if (uni) {
            float eS = __expf(S * a0);
            float e2 = eS*eS, e4 = e2*e2;
            f32x4 f = {eS, e2, e2*eS, e4};
            h0 = f*h0 + hl0;  f = f*e4;
            h1 = f*h1 + hl1;  f = f*e4;
            h2 = f*h2 + hl2;  f = f*e4;
            h3 = f*h3 + hl3;
        } else {
            f32x4 f0, f1, f2v, f3;
            #pragma unroll
            for (int j = 0; j < 4; ++j) {
                f0[j] = __expf(S*av0[j]); f1[j] = __expf(S*av1[j]);
                f2v[j] = __expf(S*av2[j]); f3[j] = __expf(S*av3[j]);
            }
            h0 = f0*h0 + hl0; h1 = f1*h1 + hl1;
            h2 = f2v*h2 + hl2; h3 = f3*h3 + hl3;
        }
    }

    if (uni) {
        for (int t = t0i; t < tend; ++t) {
            int tok = b*L_ + t;
            float dv = bf2f(dlz[(size_t)tok*DI_ + d]);
            float xv = bf2f(xcz[(size_t)tok*DI_ + d]);
            f32x4 Bv0 = bf4_to_f4(*(const ushort4*)(dbz + (size_t)tok*32 + 0));
            f32x4 Bv1 = bf4_to_f4(*(const ushort4*)(dbz + (size_t)tok*32 + 4));
            f32x4 Bv2 = bf4_to_f4(*(const ushort4*)(dbz + (size_t)tok*32 + 8));
            f32x4 Bv3 = bf4_to_f4(*(const ushort4*)(dbz + (size_t)tok*32 + 12));
            f32x4 Cv0 = bf4_to_f4(*(const ushort4*)(dbz + (size_t)tok*32 + 16));
            f32x4 Cv1 = bf4_to_f4(*(const ushort4*)(dbz + (size_t)tok*32 + 20));
            f32x4 Cv2 = bf4_to_f4(*(const ushort4*)(dbz + (size_t)tok*32 + 24));
            f32x4 Cv3 = bf4_to_f4(*(const ushort4*)(dbz + (size_t)tok*32 + 28));
            float zg = bf2f(xzz[(size_t)tok*2*DI_ + DI_ + d]);
            float du = dv * xv;
            float e1 = __expf(dv * a0);
            float e2 = e1*e1, e4 = e2*e2;
            f32x4 dA = {e1, e2, e2*e1, e4};
            h0 = dA*h0 + du*Bv0;  dA = dA*e4;
            h1 = dA*h1 + du*Bv1;  dA = dA*e4;
            h2 = dA*h2 + du*Bv2;  dA = dA*e4;
            h3 = dA*h3 + du*Bv3;
            f32x4 yv = h0*Cv0 + h1*Cv1 + h2*Cv2 + h3*Cv3;
            float y = yv[0] + yv[1] + yv[2] + yv[3];
            y = (y + Dd*xv) * (zg * sigmoidf_(zg));
            xzz[(size_t)tok*2*DI_ + d] = f2bf(y);
        }
    } else {
        for (int t = t0i; t < tend; ++t) {
            int tok = b*L_ + t;
            float dv = bf2f(dlz[(size_t)tok*DI_ + d]);
            float xv = bf2f(xcz[(size_t)tok*DI_ + d]);
            f32x4 Bv0 = bf4_to_f4(*(const ushort4*)(dbz + (size_t)tok*32 + 0));
            f32x4 Bv1 = bf4_to_f4(*(const ushort4*)(dbz + (size_t)tok*32 + 4));
            f32x4 Bv2 = bf4_to_f4(*(const ushort4*)(dbz + (size_t)tok*32 + 8));
            f32x4 Bv3 = bf4_to_f4(*(const ushort4*)(dbz + (size_t)tok*32 + 12));
            f32x4 Cv0 = bf4_to_f4(*(const ushort4*)(dbz + (size_t)tok*32 + 16));
            f32x4 Cv1 = bf4_to_f4(*(const ushort4*)(dbz + (size_t)tok*32 + 20));
            f32x4 Cv2 = bf4_to_f4(*(const ushort4*)(dbz + (size_t)tok*32 + 24));
            f32x4 Cv3 = bf4_to_f4(*(const ushort4*)(dbz + (size_t)tok*32 + 28));
            float zg = bf2f(xzz[(size_t)tok*2*DI_ + DI_ + d]);
            float du = dv * xv;
            f32x4 dA0, dA1, dA2, dA3;
            #pragma unroll
            for (int j = 0; j < 4; ++j) {
                dA0[j] = __expf(dv*av0[j]); dA1[j] = __expf(dv*av1[j]);
                dA2[j] = __expf(dv*av2[j]); dA3[j] = __expf(dv*av3[j]);
            }
            h0 = dA0*h0 + du*Bv0;
            h1 = dA1*h1 + du*Bv1;
            h2 = dA2*h2 + du*Bv2;
            h3 = dA3*h3 + du*Bv3;
            f32x4 yv = h0*Cv0 + h1*Cv1 + h2*Cv2 + h3*Cv3;
            float y = yv[0] + yv[1] + yv[2] + yv[3];
            y = (y + Dd*xv) * (zg * sigmoidf_(zg));
            xzz[(size_t)tok*2*DI_ + d] = f2bf(y);
        }
    }
}

// ============================ fused residual: t += P0 + flip(P1); tbf = bf16(t) ============================
__global__ __launch_bounds__(256) void fuse_res(float* __restrict__ t,
                                                ushort_t* __restrict__ tbf,
                                                const ushort_t* __restrict__ P)
{
    const int row4 = DM_/4;
    size_t i = (size_t)blockIdx.x*256 + threadIdx.x;
    int m = (int)(i / row4), c4 = (int)(i - (size_t)m*row4);
    int b = m / L_, l = m - b*L_;
    int mf = b*L_ + (L_-1 - l);
    float4 tv = ((float4*)t)[i];
    ushort4 p0 = ((const ushort4*)P)[(size_t)m*row4 + c4];
    ushort4 p1 = ((const ushort4*)(P + (size_t)NT_*DM_))[(size_t)mf*row4 + c4];
    tv.x += bf2f(p0.x) + bf2f(p1.x);
    tv.y += bf2f(p0.y) + bf2f(p1.y);
    tv.z += bf2f(p0.z) + bf2f(p1.z);
    tv.w += bf2f(p0.w) + bf2f(p1.w);
    ((float4*)t)[i] = tv;
    ushort4 u; u.x=f2bf(tv.x); u.y=f2bf(tv.y); u.z=f2bf(tv.z); u.w=f2bf(tv.w);
    ((ushort4*)tbf)[i] = u;
}

// ============================ launch ============================
extern "C" void kernel_launch(void* const* d_in, const int* in_sizes, int n_in,
                              void* d_out, int out_size, void* d_ws, size_t ws_size,
                              hipStream_t stream)
{
    const float* x      = (const float*)d_in[0];
    const float* rw     = (const float*)d_in[1];
    const float* rb     = (const float*)d_in[2];
    const float* lin1_w = (const float*)d_in[3];
    const float* lin1_b = (const float*)d_in[4];
    const float* head_w = (const float*)d_in[5];
    const float* head_b = (const float*)d_in[6];
    const float* ipw    = (const float*)d_in[7];
    const float* cw     = (const float*)d_in[8];
    const float* cb     = (const float*)d_in[9];
    const float* xpw    = (const float*)d_in[10];
    const float* dpw    = (const float*)d_in[11];
    const float* dpb    = (const float*)d_in[12];
    const float* A_log  = (const float*)d_in[13];
    const float* Dp     = (const float*)d_in[14];
    const float* opw    = (const float*)d_in[15];
    float* out = (float*)d_out;

    float* ws = (float*)d_ws;
    size_t off = 0;
    auto alloc = [&](size_t nfloats) { float* p = ws + off; off += (nfloats + 63) & ~(size_t)63; return p; };
    float* meanb = alloc(NT_);
    float* stdb  = alloc(NT_);
    float* psum  = alloc((size_t)B_*8*PS_);
    float* psq   = alloc((size_t)B_*8*PS_);
    ushort_t* xnt_bf = (ushort_t*)alloc((size_t)PADM_*SEQ_/2);
    ushort_t* tbf    = (ushort_t*)alloc((size_t)PADM_*DM_/2);
    float* tres  = alloc((size_t)NT_*DM_);
    ushort_t* xzb = (ushort_t*)alloc((size_t)2*PADM_*2*DI_/2);
    ushort_t* xcb = (ushort_t*)alloc((size_t)2*PADM_*DI_/2);
    ushort_t* dlb = (ushort_t*)alloc((size_t)2*NT_*DI_/2);        // bf16 delta
    ushort_t* Pb  = (ushort_t*)alloc((size_t)2*NT_*DM_/2);        // bf16 out_proj partials
    ushort_t* dbcb = (ushort_t*)alloc((size_t)2*NT_*32/2);        // bf16 B/C
    ushort_t* dtb = (ushort_t*)alloc((size_t)2*PADM_*32/2);       // bf16 dt
    ushort_t* hloc = (ushort_t*)alloc((size_t)2*16*NC_*NST_*DI_/2);
    float* Ssum  = alloc((size_t)2*16*NC_*DI_);
    ushort_t* lin1_bf = (ushort_t*)alloc((size_t)DM_*SEQ_/2);
    ushort_t* head_bf = (ushort_t*)alloc((size_t)128*DM_/2);
    ushort_t* ipw_bf  = (ushort_t*)alloc((size_t)2*2*DI_*DM_/2);
    ushort_t* opw_bf  = (ushort_t*)alloc((size_t)2*DM_*DI_/2);
    ushort_t* xpw_bf  = (ushort_t*)alloc((size_t)2*128*DI_/2);
    ushort_t* dpw_bf  = (ushort_t*)alloc((size_t)2*DI_*RNK_/2);
    (void)ws_size; (void)in_sizes; (void)n_in; (void)out_size;

    dim3 blk(256);

    CvtArgs ca;
    const float* srcs[7] = {lin1_w, head_w, ipw, opw, dpw, xpw, xpw + 64*DI_};
    ushort_t*    dsts[7] = {lin1_bf, head_bf, ipw_bf, opw_bf, dpw_bf, xpw_bf, xpw_bf + 128*DI_};
    int ns[7] = {DM_*SEQ_, PRED_*DM_, 2*2*DI_*DM_, 2*DM_*DI_, 2*DI_*RNK_, 64*DI_, 64*DI_};
    ca.start[0] = 0;
    for (int i = 0; i < 7; ++i) {
        ca.src[i] = srcs[i]; ca.dst[i] = dsts[i]; ca.n4[i] = ns[i]/4;
        ca.start[i+1] = ca.start[i] + (ca.n4[i] + 255)/256;
    }
    cvt_all<<<dim3(ca.start[7]), blk, 0, stream>>>(ca);

    revin_partial<<<dim3(B_, 6, 8), blk, 0, stream>>>(x, psum, psq);
    revin_final<<<dim3(B_), dim3(384), 0, stream>>>(psum, psq, meanb, stdb);
    norm_transpose<<<dim3(B_, 8, 6), blk, 0, stream>>>(x, meanb, stdb, rw, rb, xnt_bf);
    gemm_bf16<64><<<dim3(41, 4, 1), blk, 0, stream>>>(xnt_bf, SEQ_, 0, lin1_bf, SEQ_, 0,
                                                      NT_, DM_, SEQ_,
                                                      EpiBiasDual{tres, tbf, lin1_b});

    for (int layer = 0; layer < 2; ++layer) {
        // in_proj, both dirs merged into one N=4096 GEMM (dir = n>>11 in epilogue)
        gemm_bf16<64><<<dim3(41, 32, 1), blk, 0, stream>>>(
            tbf, DM_, 0, ipw_bf, DM_, 0,
            NT_, 2*2*DI_, DM_, EpiXZ2{xzb});
        conv_silu<<<dim3(NT_, 2), blk, 0, stream>>>(xzb, cw, cb, xcb);
        // x_proj (both dirs): dt -> bf16 dtb, B/C -> bf16 dbcb
        gemm_bf16<64><<<dim3(41, 1, 2), blk, 0, stream>>>(
            xcb, DI_, (size_t)PADM_*DI_, xpw_bf, DI_, (size_t)128*DI_,
            NT_, 64, DI_, EpiDbl{dbcb, dtb});
        // delta (both dirs): softplus(dt @ dpw^T + dpb) -> bf16   [MFMA K=32]
        gemm_bf16<32><<<dim3(41, 8, 2), blk, 0, stream>>>(
            dtb, 32, (size_t)PADM_*32, dpw_bf, 32, (size_t)DI_*RNK_,
            NT_, DI_, RNK_, EpiSpB{dlb, dpb});
        // chunked scan (both dirs); p2 composes carries inline
        scan_p1<<<dim3(16, NC_-1, 32), dim3(64), 0, stream>>>(dlb, xcb, dbcb, A_log, hloc, Ssum);
        scan_p2<<<dim3(16, NC_, 32), dim3(64), 0, stream>>>(dlb, xcb, xzb, dbcb, A_log, Dp, hloc, Ssum);
        // out_proj (both dirs, one z=2 dispatch): P[z] = y @ opw[z]^T (bf16 partials)
        gemm_bf16<64><<<dim3(41, 4, 2), blk, 0, stream>>>(
            xzb, 2*DI_, (size_t)PADM_*2*DI_, opw_bf, DI_, (size_t)DM_*DI_,
            NT_, DM_, DI_, EpiP{Pb});
        // residual: t += P0 + flip(P1); tbf = bf16(t)
        fuse_res<<<dim3((NT_*DM_/4)/256), blk, 0, stream>>>(tres, tbf, Pb);
    }
    gemm_bf16<64><<<dim3(41, 1, 1), blk, 0, stream>>>(tbf, DM_, 0, head_bf, DM_, 0,
                                                      NT_, PRED_, DM_,
                                                      EpiHead{out, head_b, meanb, stdb, rw, rb});
}